// Round 7
// baseline (959.836 us; speedup 1.0000x reference)
//
#include <hip/hip_runtime.h>
#include <hip/hip_fp16.h>

#define U_CNT 100001
#define I_CNT 50001
#define N_CNT 150002
#define DIM 64
#define BROWS 128                           // rows per bucket
#define NB2 ((N_CNT + BROWS - 1) / BROWS)   // 1172 buckets
#define CH 8192                             // edges per partition block
#define WCAP 12288                          // binplace LDS window capacity

__device__ inline __half2 u2h(unsigned int u) { union { unsigned int u; __half2 h; } c; c.u = u; return c.h; }
__device__ inline unsigned int h2u(__half2 h) { union { unsigned int u; __half2 h; } c; c.h = h; return c.u; }

// LDS-privatized bucket histogram (1172 bins) — no per-row global atomics
__global__ void bucket_hist(const int* __restrict__ rows, int* __restrict__ bhist,
                            int nnz) {
    __shared__ int lh[NB2];
    for (int i = threadIdx.x; i < NB2; i += blockDim.x) lh[i] = 0;
    __syncthreads();
    int stride = gridDim.x * blockDim.x;
    for (int i = blockIdx.x * blockDim.x + threadIdx.x; i < nnz; i += stride)
        atomicAdd(&lh[rows[i] >> 7], 1);
    __syncthreads();
    for (int i = threadIdx.x; i < NB2; i += blockDim.x) {
        int v = lh[i];
        if (v) atomicAdd(&bhist[i], v);
    }
}

// parallel scan of 1172 bucket totals -> bucket_ptr[NB2+1], bcur init
__global__ void bucket_scan(const int* __restrict__ bhist,
                            int* __restrict__ bucket_ptr,
                            int* __restrict__ bcur) {
    __shared__ int lds[1024];
    int t = threadIdx.x;
    int b0 = t * 2;
    int b1 = b0 + 2; if (b1 > NB2) b1 = NB2;
    int s = 0;
    for (int i = b0; i < b1 && i < NB2; ++i) s += bhist[i];
    lds[t] = s;
    __syncthreads();
    for (int off = 1; off < 1024; off <<= 1) {
        int v = (t >= off) ? lds[t - off] : 0;
        __syncthreads();
        lds[t] += v;
        __syncthreads();
    }
    int run = (t == 0) ? 0 : lds[t - 1];
    for (int i = b0; i < b1 && i < NB2; ++i) {
        bucket_ptr[i] = run;
        bcur[i] = run;
        run += bhist[i];
    }
    if (t == 1023) bucket_ptr[NB2] = lds[1023];
}

// phase A: block-local counting sort of an 8192-edge chunk into 1172 buckets,
// then contiguous run-writes to global staging. Record = (col<<7)|(row&127).
__global__ void __launch_bounds__(256) partition_kernel(
    const int* __restrict__ rows, const int* __restrict__ cols,
    int* __restrict__ bcur, unsigned int* __restrict__ staging, int nnz)
{
    __shared__ int hist[NB2];
    __shared__ int ofs[NB2 + 1];
    __shared__ int cur[NB2];
    __shared__ int gbase[NB2];
    __shared__ int tsum[256];
    __shared__ unsigned int recs[CH];
    const int t = threadIdx.x;
    int base = blockIdx.x * CH;
    int lim = nnz - base; if (lim > CH) lim = CH;

    for (int i = t; i < NB2; i += 256) hist[i] = 0;
    __syncthreads();
    // 1: histogram
    for (int i = t; i < lim; i += 256)
        atomicAdd(&hist[rows[base + i] >> 7], 1);
    __syncthreads();
    // 2: two-level exclusive scan (5 bins per thread)
    int b0 = t * 5;
    int b1 = b0 + 5; if (b1 > NB2) b1 = NB2;
    int s = 0;
    for (int i = b0; i < b1; ++i) s += hist[i];
    tsum[t] = s;
    __syncthreads();
    for (int off = 1; off < 256; off <<= 1) {
        int v = (t >= off) ? tsum[t - off] : 0;
        __syncthreads();
        tsum[t] += v;
        __syncthreads();
    }
    int run = (t == 0) ? 0 : tsum[t - 1];
    for (int i = b0; i < b1; ++i) {
        ofs[i] = run;
        cur[i] = run;
        run += hist[i];
    }
    if (t == 0) ofs[NB2] = lim;
    __syncthreads();
    // 3: reserve global space per bucket
    for (int i = t; i < NB2; i += 256) {
        int cnt = hist[i];
        if (cnt) gbase[i] = atomicAdd(&bcur[i], cnt);
    }
    // 4: local scatter into recs at scanned positions
    for (int i = t; i < lim; i += 256) {
        int r = rows[base + i];
        int c = cols[base + i];
        int p = atomicAdd(&cur[r >> 7], 1);
        recs[p] = ((unsigned int)c << 7) | (unsigned int)(r & (BROWS - 1));
    }
    __syncthreads();
    // 5: coalesced run-writes; bucket of position p via binary search in ofs
    for (int p = t; p < lim; p += 256) {
        unsigned int rec = recs[p];
        int lo = 0, hi = NB2;
        while (hi - lo > 1) {
            int mid = (lo + hi) >> 1;
            if (ofs[mid] <= p) lo = mid; else hi = mid;
        }
        staging[gbase[lo] + (p - ofs[lo])] = rec;
    }
}

// phase B: one block per 128-row bucket. Per-row degrees (LDS hist) -> LDS
// scan -> row_ptr + dinv; place cols into an LDS window, stream out coalesced.
__global__ void __launch_bounds__(256) binplace_kernel(
    const int* __restrict__ bucket_ptr,
    const unsigned int* __restrict__ staging,
    unsigned int* __restrict__ col_s,
    int* __restrict__ row_ptr,
    float* __restrict__ dinv)
{
    __shared__ int hist[BROWS];
    __shared__ int cur[BROWS];
    __shared__ unsigned int win[WCAP];
    int b = blockIdx.x;
    int base = b << 7;
    int beg = bucket_ptr[b];
    int end = bucket_ptr[b + 1];
    int tot = end - beg;
    int t = threadIdx.x;
    if (t < BROWS) hist[t] = 0;
    __syncthreads();
    for (int j = beg + t; j < end; j += 256)
        atomicAdd(&hist[staging[j] & (BROWS - 1u)], 1);
    __syncthreads();
    int cnt = (t < BROWS) ? hist[t] : 0;
    for (int off = 1; off < BROWS; off <<= 1) {
        int v = (t < BROWS && t >= off) ? hist[t - off] : 0;
        __syncthreads();
        if (t < BROWS) hist[t] += v;
        __syncthreads();
    }
    if (t < BROWS) {
        int excl = hist[t] - cnt;              // window-relative
        cur[t] = excl;
        int r = base + t;
        if (r < N_CNT) {
            row_ptr[r] = beg + excl;
            dinv[r] = 1.0f / sqrtf((float)cnt + 1e-7f);
        }
    }
    if (b == NB2 - 1 && t == 0) row_ptr[N_CNT] = end;
    __syncthreads();
    if (tot <= WCAP) {
        for (int j = beg + t; j < end; j += 256) {
            unsigned int rec = staging[j];
            int pos = atomicAdd(&cur[rec & (BROWS - 1u)], 1);
            win[pos] = rec >> 7;
        }
        __syncthreads();
        for (int p = t; p < tot; p += 256)
            col_s[beg + p] = win[p];
    } else {
        for (int j = beg + t; j < end; j += 256) {
            unsigned int rec = staging[j];
            int pos = atomicAdd(&cur[rec & (BROWS - 1u)], 1);
            col_s[beg + pos] = rec >> 7;
        }
    }
}

// init: hs0 = fp16(dinv .* emb) ; acc = emb (f32)
__global__ void init_kernel(const float4* __restrict__ ue,
                            const float4* __restrict__ ie,
                            const float* __restrict__ dinv,
                            uint4* __restrict__ hs,
                            float4* __restrict__ acc) {
    int i = blockIdx.x * blockDim.x + threadIdx.x;   // over N_CNT*8
    if (i >= N_CNT * 8) return;
    int node = i >> 3;
    int s = i & 7;
    float d = dinv[node];
    size_t fo = (size_t)node * 16 + s * 2;
    float4 v0, v1;
    if (node < U_CNT) { v0 = ue[fo]; v1 = ue[fo + 1]; }
    else { size_t io = fo - (size_t)U_CNT * 16; v0 = ie[io]; v1 = ie[io + 1]; }
    acc[fo] = v0;
    acc[fo + 1] = v1;
    uint4 h;
    h.x = h2u(__floats2half2_rn(d * v0.x, d * v0.y));
    h.y = h2u(__floats2half2_rn(d * v0.z, d * v0.w));
    h.z = h2u(__floats2half2_rn(d * v1.x, d * v1.y));
    h.w = h2u(__floats2half2_rn(d * v1.z, d * v1.w));
    hs[(size_t)node * 8 + s] = h;
}

__device__ inline void acc8(float4& a0, float4& a1, uint4 u) {
    float2 f;
    f = __half22float2(u2h(u.x)); a0.x += f.x; a0.y += f.y;
    f = __half22float2(u2h(u.y)); a0.z += f.x; a0.w += f.y;
    f = __half22float2(u2h(u.z)); a1.x += f.x; a1.y += f.y;
    f = __half22float2(u2h(u.w)); a1.z += f.x; a1.w += f.y;
}

// split-D gather SpMM: 4 lanes per row, each lane 16B; halfsel picks which
// 64B half of each row is gathered/written (one cache line per edge).
__global__ void __launch_bounds__(256) spmm_gather(
    const int* __restrict__ row_ptr,
    const unsigned int* __restrict__ col_s,
    const float* __restrict__ dinv,
    const uint4* __restrict__ x,
    uint4* __restrict__ y,
    float4* __restrict__ acc,
    int r0, int r1, int halfsel, int last)
{
    int r = r0 + blockIdx.x * 64 + (threadIdx.x >> 2);
    int s = threadIdx.x & 3;
    if (r >= r1) return;
    int beg = row_ptr[r];
    int end = row_ptr[r + 1];
    int hb = (halfsel << 2) + s;                 // uint4 offset within row
    float4 a0 = {0.f, 0.f, 0.f, 0.f}, a1 = {0.f, 0.f, 0.f, 0.f};
    float4 b0 = {0.f, 0.f, 0.f, 0.f}, b1 = {0.f, 0.f, 0.f, 0.f};
    int j = beg;
    for (; j + 4 <= end; j += 4) {
        unsigned int c0 = col_s[j];
        unsigned int c1 = col_s[j + 1];
        unsigned int c2 = col_s[j + 2];
        unsigned int c3 = col_s[j + 3];
        uint4 u0 = x[(size_t)c0 * 8 + hb];
        uint4 u1 = x[(size_t)c1 * 8 + hb];
        uint4 u2 = x[(size_t)c2 * 8 + hb];
        uint4 u3 = x[(size_t)c3 * 8 + hb];
        acc8(a0, a1, u0);
        acc8(b0, b1, u1);
        acc8(a0, a1, u2);
        acc8(b0, b1, u3);
    }
    for (; j < end; ++j) {
        unsigned int c0 = col_s[j];
        uint4 u0 = x[(size_t)c0 * 8 + hb];
        acc8(a0, a1, u0);
    }
    a0.x += b0.x; a0.y += b0.y; a0.z += b0.z; a0.w += b0.w;
    a1.x += b1.x; a1.y += b1.y; a1.z += b1.z; a1.w += b1.w;

    float d = dinv[r];
    float d2 = d * d;
    uint4 h;
    h.x = h2u(__floats2half2_rn(d2 * a0.x, d2 * a0.y));
    h.y = h2u(__floats2half2_rn(d2 * a0.z, d2 * a0.w));
    h.z = h2u(__floats2half2_rn(d2 * a1.x, d2 * a1.y));
    h.w = h2u(__floats2half2_rn(d2 * a1.z, d2 * a1.w));
    y[(size_t)r * 8 + hb] = h;

    size_t o = (size_t)r * 16 + (halfsel << 3) + s * 2;
    float4 c0 = acc[o];
    float4 c1 = acc[o + 1];
    c0.x += d * a0.x; c0.y += d * a0.y; c0.z += d * a0.z; c0.w += d * a0.w;
    c1.x += d * a1.x; c1.y += d * a1.y; c1.z += d * a1.z; c1.w += d * a1.w;
    if (last) {
        c0.x *= 0.25f; c0.y *= 0.25f; c0.z *= 0.25f; c0.w *= 0.25f;
        c1.x *= 0.25f; c1.y *= 0.25f; c1.z *= 0.25f; c1.w *= 0.25f;
    }
    acc[o] = c0;
    acc[o + 1] = c1;
}

extern "C" void kernel_launch(void* const* d_in, const int* in_sizes, int n_in,
                              void* d_out, int out_size, void* d_ws, size_t ws_size,
                              hipStream_t stream) {
    const float* ue   = (const float*)d_in[0];
    const float* ie   = (const float*)d_in[1];
    const int*   rows = (const int*)d_in[2];
    const int*   cols = (const int*)d_in[3];
    int nnz = in_sizes[2];

    float* acc = (float*)d_out;

    unsigned int* ws = (unsigned int*)d_ws;
    uint4* hs0 = (uint4*)ws;                               // N*8 uint4 (fp16 hs)
    uint4* hs1 = hs0 + (size_t)N_CNT * 8;                  // N*8 uint4
    int*   row_ptr    = (int*)(hs1 + (size_t)N_CNT * 8);   // N+1
    int*   bhist      = row_ptr + (N_CNT + 1);             // NB2
    int*   bucket_ptr = bhist + NB2;                       // NB2+1
    int*   bcur       = bucket_ptr + (NB2 + 1);            // NB2
    float* dinv       = (float*)(bcur + NB2);              // N
    unsigned int* staging = (unsigned int*)(dinv + N_CNT); // nnz
    unsigned int* col_s   = staging + nnz;                 // nnz

    const int tpb = 256;

    // ---- CSR build: bucket totals (LDS hist), scan, partition, place ----
    hipMemsetAsync(bhist, 0, NB2 * sizeof(int), stream);
    bucket_hist<<<512, tpb, 0, stream>>>(rows, bhist, nnz);
    bucket_scan<<<1, 1024, 0, stream>>>(bhist, bucket_ptr, bcur);
    partition_kernel<<<(nnz + CH - 1) / CH, tpb, 0, stream>>>(
        rows, cols, bcur, staging, nnz);
    binplace_kernel<<<NB2, tpb, 0, stream>>>(
        bucket_ptr, staging, col_s, row_ptr, dinv);

    // ---- dinv-scaled initial embeddings ----
    init_kernel<<<(N_CNT * 8 + tpb - 1) / tpb, tpb, 0, stream>>>(
        (const float4*)ue, (const float4*)ie, dinv, hs0, (float4*)acc);

    // ---- 3 propagation layers, split by direction and by D-half ----
    uint4* cur = hs0;
    uint4* nxt = hs1;
    const int ublocks = (U_CNT + 63) / 64;
    const int iblocks = (I_CNT + 63) / 64;
    for (int l = 0; l < 3; ++l) {
        int last = (l == 2) ? 1 : 0;
        spmm_gather<<<ublocks, tpb, 0, stream>>>(
            row_ptr, col_s, dinv, cur, nxt, (float4*)acc, 0, U_CNT, 0, last);
        spmm_gather<<<ublocks, tpb, 0, stream>>>(
            row_ptr, col_s, dinv, cur, nxt, (float4*)acc, 0, U_CNT, 1, last);
        spmm_gather<<<iblocks, tpb, 0, stream>>>(
            row_ptr, col_s, dinv, cur, nxt, (float4*)acc, U_CNT, N_CNT, 0, last);
        spmm_gather<<<iblocks, tpb, 0, stream>>>(
            row_ptr, col_s, dinv, cur, nxt, (float4*)acc, U_CNT, N_CNT, 1, last);
        uint4* tmp = cur; cur = nxt; nxt = tmp;
    }
}